// Round 7
// baseline (69.941 us; speedup 1.0000x reference)
//
#include <hip/hip_runtime.h>
#include <math.h>

#define NB 64
#define Q 900
#define NC 81
#define NC2 80
#define HD 256
#define NV 117
#define NEGV -1000000000.0f

// ---------------- ws layout (bytes) ----------------
static const size_t OFF_SCORES = 0;          // f32 [NB*Q]
static const size_t OFF_LABELS = 230400;     // i32 [NB*Q]

typedef float float4u __attribute__((ext_vector_type(4), aligned(4)));

// ---------------- K1: scores / labels (4-lane quad per row, float4 loads) ----------------
__global__ __launch_bounds__(256) void k_score(const float* __restrict__ logits,
                                               float* __restrict__ scores,
                                               int* __restrict__ labels) {
  int quad = threadIdx.x >> 2, qq = threadIdx.x & 3;
  int row = blockIdx.x * 64 + quad;          // grid = 900 -> 57600 rows exactly
  const float* lp = logits + (size_t)row * NC;
  float4u x[5];
  #pragma unroll
  for (int j = 0; j < 5; j++) {
    int c = qq + 4 * j;                      // chunk 0..19, covers idx 0..79
    x[j] = *(const float4u*)(lp + c * 4);
  }
  float x80 = (qq == 0) ? lp[80] : -INFINITY;
  float m = x80;
  #pragma unroll
  for (int j = 0; j < 5; j++)
    m = fmaxf(m, fmaxf(fmaxf(x[j].x, x[j].y), fmaxf(x[j].z, x[j].w)));
  m = fmaxf(m, __shfl_xor(m, 1));
  m = fmaxf(m, __shfl_xor(m, 2));
  float e = (qq == 0) ? expf(x80 - m) : 0.0f;
  #pragma unroll
  for (int j = 0; j < 5; j++)
    e += expf(x[j].x - m) + expf(x[j].y - m) + expf(x[j].z - m) + expf(x[j].w - m);
  e += __shfl_xor(e, 1);
  e += __shfl_xor(e, 2);
  float bv = -INFINITY; int bi = 0x7fffffff;
  #pragma unroll
  for (int j = 0; j < 5; j++) {
    int base = (qq + 4 * j) * 4;
    if (x[j].x > bv) { bv = x[j].x; bi = base; }
    if (x[j].y > bv) { bv = x[j].y; bi = base + 1; }
    if (x[j].z > bv) { bv = x[j].z; bi = base + 2; }
    if (x[j].w > bv) { bv = x[j].w; bi = base + 3; }
  }
  #pragma unroll
  for (int s = 1; s <= 2; s <<= 1) {
    float ov = __shfl_xor(bv, s); int oi = __shfl_xor(bi, s);
    if (ov > bv || (ov == bv && oi < bi)) { bv = ov; bi = oi; }
  }
  if (qq == 0) {
    scores[row] = expf(bv - m) / e;
    labels[row] = bi;
  }
}

// ---------------- K2: NMS + topk + GEMM slice + epilogue (1 block per img,slice) -------
// Packed output cols (125 wide, padded to 128): [0,117) = Wv verb, [117,125) = Wb bbox.
// Slice s owns packed cols [s*32, s*32+32). Ch rows use W rows 0..255, Co rows 256..511.
__global__ __launch_bounds__(1024) void k_back(const float* __restrict__ scores,
                                               const int* __restrict__ labels,
                                               const float* __restrict__ boxes,
                                               const float* __restrict__ hs,
                                               const float* __restrict__ sizes,
                                               const float* __restrict__ Wv,
                                               const float* __restrict__ bverb,
                                               const float* __restrict__ Wb,
                                               const float* __restrict__ bbox,
                                               float* __restrict__ out) {
  int slice = blockIdx.x, img = blockIdx.y;
  int t = threadIdx.x, w = t >> 6, lane = t & 63;
  size_t imgQ = (size_t)img * Q;

  // front region (aliased by GEMM A-tile later)
  __shared__ __attribute__((aligned(16))) float s_front[9248];
  float* s_box = s_front;                    // [900*4]
  float* s_sc  = s_front + 3600;             // [900]
  int*   s_lab = (int*)(s_front + 4500);     // [900]
  float* s_hsc = s_front + 5400;             // [900]
  float* s_osc = s_front + 6300;             // [900]
  int*   s_gidx = (int*)(s_front + 7200);    // [16*64]
  int*   s_gsrt = (int*)(s_front + 8224);    // [16*64]
  float* s_A   = s_front;                    // alias: [30][256] = 7680 floats
  // dedicated
  __shared__ float s_wmax[16];
  __shared__ int   s_tki[30];
  __shared__ float s_tkv[30];
  __shared__ int   s_tkval[30];
  __shared__ float s_pr[225];
  __shared__ float s_box30[120];
  __shared__ float s_B[2][64][32];           // B chunk: [h/o][k][c]
  __shared__ float s_Cg[30][32];

  // ---- stage boxes + box max + scores/labels ----
  const float4* bp4 = (const float4*)(boxes + imgQ * 4);
  float bm = -INFINITY;
  if (t < Q) {
    float4 v = bp4[t];
    ((float4*)s_box)[t] = v;
    bm = fmaxf(fmaxf(v.x, v.y), fmaxf(v.z, v.w));
    s_sc[t]  = scores[imgQ + t];
    s_lab[t] = labels[imgQ + t];
    s_hsc[t] = NEGV;
    s_osc[t] = NEGV;
  }
  #pragma unroll
  for (int s = 32; s > 0; s >>= 1) bm = fmaxf(bm, __shfl_xor(bm, s));
  if (lane == 0) s_wmax[w] = bm;
  __syncthreads();

  float bmax = s_wmax[0];
  #pragma unroll
  for (int i = 1; i < 16; i++) bmax = fmaxf(bmax, s_wmax[i]);

  // ---- per-class greedy NMS: wave w handles classes w*5 .. w*5+4 ----
  {
#pragma clang fp contract(off)
    unsigned long long lmask = (1ull << lane) - 1ull;
    for (int cc = 0; cc < 5; cc++) {
      int c = w * 5 + cc;
      int lb[15]; float sc[15];
      #pragma unroll
      for (int e = 0; e < 15; e++) {
        int i = e * 64 + lane;
        lb[e] = (i < Q) ? s_lab[i] : -1;
        sc[e] = (i < Q) ? s_sc[i] : 0.0f;
      }
      int n = 0;
      #pragma unroll
      for (int e = 0; e < 15; e++) {
        bool memb = (lb[e] == c);
        unsigned long long mm = __ballot(memb);
        if (memb) {
          int pos = n + __popcll(mm & lmask);
          if (pos < 64) s_gidx[w * 64 + pos] = e * 64 + lane;
        }
        n += __popcll(mm);
      }
      n = min(n, 64);
      int   myidx = (lane < n) ? s_gidx[w * 64 + lane] : 0;
      float mysc  = (lane < n) ? s_sc[myidx] : -INFINITY;

      int rank = 0;
      for (int j = 0; j < n; j++) {
        float sj = __shfl(mysc, j);
        rank += (sj > mysc) || (sj == mysc && j < lane);
      }
      if (lane < n) s_gsrt[w * 64 + rank] = myidx;
      int oi = (lane < n) ? s_gsrt[w * 64 + lane] : 0;
      float os = (lane < n) ? s_sc[oi] : 0.0f;

      float b0 = 0.f, b1 = 0.f, b2 = 0.f, b3 = 0.f;
      if (lane < n) {
        float off = (float)c * (bmax + 1.0f);
        b0 = s_box[oi * 4 + 0] + off; b1 = s_box[oi * 4 + 1] + off;
        b2 = s_box[oi * 4 + 2] + off; b3 = s_box[oi * 4 + 3] + off;
      }
      float areaA = (b2 - b0) * (b3 - b1);

      unsigned long long sup = 0;
      for (int j = 0; j < n; j++) {
        float c0 = __shfl(b0, j), c1 = __shfl(b1, j);
        float c2 = __shfl(b2, j), c3 = __shfl(b3, j);
        if (j > lane && lane < n) {
          float ltx = fmaxf(b0, c0), lty = fmaxf(b1, c1);
          float rbx = fminf(b2, c2), rby = fminf(b3, c3);
          float ww = fmaxf(rbx - ltx, 0.0f), hh = fmaxf(rby - lty, 0.0f);
          float inter = ww * hh;
          float areaB = (c2 - c0) * (c3 - c1);
          float uni = areaA + areaB - inter;
          float denom = (uni == 0.0f) ? 1.0f : uni;
          if (inter / denom > 0.5f) sup |= (1ull << j);
        }
      }

      unsigned long long keepm = (n >= 64) ? ~0ull : ((1ull << n) - 1ull);
      for (int i = 0; i < n; i++) {
        unsigned long long row = __shfl(sup, i);
        if ((keepm >> i) & 1ull) keepm &= ~row;
      }

      if (lane < n) {
        int kept = (int)((keepm >> lane) & 1ull);
        float val = kept ? os : NEGV;
        if (c == 0) s_hsc[oi] = val;
        else        s_osc[oi] = val;
      }
    }
  }
  __syncthreads();

  // ---- topk: wave0 = humans, wave1 = objects ----
  if (w < 2) {
    const float* src = (w == 0) ? s_hsc : s_osc;
    float v[15];
    int cnt = 0;
    #pragma unroll
    for (int e = 0; e < 15; e++) {
      int i = e * 64 + lane;
      float val = (i < Q) ? src[i] : -INFINITY;
      cnt += (val >= 0.2f) ? 1 : 0;
      v[e] = val;
    }
    #pragma unroll
    for (int s = 32; s > 0; s >>= 1) cnt += __shfl_xor(cnt, s);

    float selv = 0.f; int seli = 0;
    for (int r = 0; r < 15; r++) {
      float bv_ = -INFINITY; int bi_ = 0x7fffffff;
      #pragma unroll
      for (int e = 0; e < 15; e++) { if (v[e] > bv_) { bv_ = v[e]; bi_ = e * 64 + lane; } }
      #pragma unroll
      for (int s = 32; s > 0; s >>= 1) {
        float ov = __shfl_xor(bv_, s); int oi2 = __shfl_xor(bi_, s);
        if (ov > bv_ || (ov == bv_ && oi2 < bi_)) { bv_ = ov; bi_ = oi2; }
      }
      if (lane == r) { selv = bv_; seli = bi_; }
      if ((bi_ & 63) == lane) {
        int ee = bi_ >> 6;
        #pragma unroll
        for (int e = 0; e < 15; e++) if (e == ee) v[e] = -2.0e9f;
      }
    }
    int kk = min(max(cnt, 3), 15);
    if (lane < 15) {
      s_tki[w * 15 + lane]   = seli;
      s_tkv[w * 15 + lane]   = selv;
      s_tkval[w * 15 + lane] = (lane < kk && selv > -5.0e8f) ? 1 : 0;
    }
  }
  __syncthreads();

  // ---- pair products + snapshot 30 selected boxes (front region dies after this) ----
  if (t < 225) {
    int h_ = t / 15, o_ = t - h_ * 15;
    float th = s_tkv[h_], to_ = s_tkv[15 + o_];
    s_pr[t] = (s_tkval[h_] && s_tkval[15 + o_]) ? th * to_ : 0.0f;
  }
  if (t < 120) {
    int r = t >> 2, j = t & 3;
    s_box30[t] = s_box[s_tki[r] * 4 + j];
  }
  __syncthreads();

  // ---- stage A (30 gathered hs rows, overwrites front) ----
  for (int f = t; f < 1920; f += 1024) {
    int r = f >> 6, q = f & 63;
    float4 a = *(const float4*)(hs + (imgQ + s_tki[r]) * HD + q * 4);
    ((float4*)s_A)[r * 64 + q] = a;
  }

  // ---- GEMM: Ch/Co rows x 32 packed cols, K chunked by 64 ----
  int col = slice * 32 + (t & 31);           // packed col this thread covers in staging
  int r = t >> 5, c = t & 31;                // GEMM output coords (r<30)
  float acc = 0.0f;
  for (int kc = 0; kc < 256; kc += 64) {
    __syncthreads();                          // A ready (first iter) / prev chunk consumed
    for (int idx = t; idx < 4096; idx += 1024) {
      int half = idx >> 11, rem = idx & 2047;
      int k_l = rem >> 5, c_l = rem & 31;
      int pcol = slice * 32 + c_l;
      int kg = kc + k_l + (half ? 256 : 0);
      float val = 0.0f;
      if (pcol < 117)      val = Wv[(size_t)kg * 117 + pcol];
      else if (pcol < 125) val = Wb[(size_t)kg * 8 + (pcol - 117)];
      s_B[half][k_l][c_l] = val;
    }
    __syncthreads();
    if (r < 30) {
      const float* Bp = &s_B[r < 15 ? 0 : 1][0][0];
      #pragma unroll
      for (int kk = 0; kk < 64; kk += 4) {
        float4 a4 = *(const float4*)(s_A + r * 256 + kc + kk);
        acc += a4.x * Bp[(kk + 0) * 32 + c];
        acc += a4.y * Bp[(kk + 1) * 32 + c];
        acc += a4.z * Bp[(kk + 2) * 32 + c];
        acc += a4.w * Bp[(kk + 3) * 32 + c];
      }
    }
  }
  if (r < 30) s_Cg[r][c] = acc;
  __syncthreads();

  // ---- epilogue ----
  float hgt = sizes[img * 2 + 0], wid = sizes[img * 2 + 1];
  float* out0 = out;
  float* out1 = out + 7680;
  float* out2 = out + 65280;
  float* out3 = out + 122880;

  // verb sigmoid for this slice's cols
  int veff = (slice < 3) ? 32 : 21;          // slice 3: packed cols 96..116 are verb
  for (int e = t; e < 225 * veff; e += 1024) {
    int p = e / veff, cl = e - p * veff;
    int ph = p / 15, po = p - ph * 15;
    int v = slice * 32 + cl;
    float x = s_Cg[ph][cl] + s_Cg[15 + po][cl] + bverb[v];
    out3[(size_t)img * 26325 + p * NV + v] = (1.0f / (1.0f + expf(-x))) * s_pr[p];
  }

  if (slice == 3) {
    if (t < 30) {
      const float* bp = s_box30 + t * 4;
      float cx = bp[0], cy = bp[1], ww = bp[2], hh = bp[3];
      float* o = out0 + ((size_t)img * 30 + t) * 4;
      o[0] = (cx - 0.5f * ww) * wid;
      o[1] = (cy - 0.5f * hh) * hgt;
      o[2] = (cx + 0.5f * ww) * wid;
      o[3] = (cy + 0.5f * hh) * hgt;
    }
    if (t < 225) {
      int h_ = t / 15, o_ = t - h_ * 15;
      // bbox cols are packed 117..124 -> local 21..28 on slice 3
      {
        float d0 = s_Cg[h_][21] + s_Cg[15 + o_][21] + bbox[0];
        float d1 = s_Cg[h_][22] + s_Cg[15 + o_][22] + bbox[1];
        float d2 = s_Cg[h_][23] + s_Cg[15 + o_][23] + bbox[2];
        float d3 = s_Cg[h_][24] + s_Cg[15 + o_][24] + bbox[3];
        const float* bp = s_box30 + h_ * 4;
        float cx = bp[0], cy = bp[1], ww = bp[2], hh = bp[3];
        float cx2 = cx + d0 * ww, cy2 = cy + d1 * hh;
        float w2 = ww * expf(d2), h2 = hh * expf(d3);
        float* o = out1 + ((size_t)img * 225 + t) * 4;
        o[0] = (cx2 - 0.5f * w2) * wid;
        o[1] = (cy2 - 0.5f * h2) * hgt;
        o[2] = (cx2 + 0.5f * w2) * wid;
        o[3] = (cy2 + 0.5f * h2) * hgt;
      }
      {
        float d4 = s_Cg[h_][25] + s_Cg[15 + o_][25] + bbox[4];
        float d5 = s_Cg[h_][26] + s_Cg[15 + o_][26] + bbox[5];
        float d6 = s_Cg[h_][27] + s_Cg[15 + o_][27] + bbox[6];
        float d7 = s_Cg[h_][28] + s_Cg[15 + o_][28] + bbox[7];
        const float* bp = s_box30 + (15 + o_) * 4;
        float cx = bp[0], cy = bp[1], ww = bp[2], hh = bp[3];
        float cx2 = cx + d4 * ww, cy2 = cy + d5 * hh;
        float w2 = ww * expf(d6), h2 = hh * expf(d7);
        float* o = out2 + ((size_t)img * 225 + t) * 4;
        o[0] = (cx2 - 0.5f * w2) * wid;
        o[1] = (cy2 - 0.5f * h2) * hgt;
        o[2] = (cx2 + 0.5f * w2) * wid;
        o[3] = (cy2 + 0.5f * h2) * hgt;
      }
    }
  }
}

extern "C" void kernel_launch(void* const* d_in, const int* in_sizes, int n_in,
                              void* d_out, int out_size, void* d_ws, size_t ws_size,
                              hipStream_t stream) {
  const float* logits = (const float*)d_in[0];
  const float* boxes  = (const float*)d_in[1];
  const float* hs     = (const float*)d_in[2];
  const float* sizes  = (const float*)d_in[3];
  const float* Wv     = (const float*)d_in[4];
  const float* bv     = (const float*)d_in[5];
  const float* Wb     = (const float*)d_in[6];
  const float* bb     = (const float*)d_in[7];
  float* out = (float*)d_out;
  char* ws = (char*)d_ws;

  float* scores = (float*)(ws + OFF_SCORES);
  int*   labels = (int*)(ws + OFF_LABELS);

  k_score<<<900, 256, 0, stream>>>(logits, scores, labels);
  k_back<<<dim3(4, NB), 1024, 0, stream>>>(scores, labels, boxes, hs, sizes,
                                           Wv, bv, Wb, bb, out);
}

// Round 8
// 52.371 us; speedup vs baseline: 1.3355x; 1.3355x over previous
//
#include <hip/hip_runtime.h>
#include <math.h>

#define NB 64
#define Q 900
#define NC 81
#define NC2 80
#define HD 256
#define NV 117
#define NEGV -1000000000.0f

// ---------------- ws layout (bytes) ----------------
static const size_t OFF_SCORES = 0;          // f32 [NB*Q]
static const size_t OFF_LABELS = 230400;     // i32 [NB*Q]
static const size_t OFF_HSC    = 460800;     // f32 [NB*Q] masked human scores
static const size_t OFF_OSC    = 691200;     // f32 [NB*Q] masked object scores

typedef float float4u __attribute__((ext_vector_type(4), aligned(4)));

// ---------------- K1: scores / labels (4-lane quad per row, float4 loads) ----------------
__global__ __launch_bounds__(256) void k_score(const float* __restrict__ logits,
                                               float* __restrict__ scores,
                                               int* __restrict__ labels) {
  int quad = threadIdx.x >> 2, qq = threadIdx.x & 3;
  int row = blockIdx.x * 64 + quad;          // grid = 900 -> 57600 rows exactly
  const float* lp = logits + (size_t)row * NC;
  float4u x[5];
  #pragma unroll
  for (int j = 0; j < 5; j++) {
    int c = qq + 4 * j;                      // chunk 0..19, covers idx 0..79
    x[j] = *(const float4u*)(lp + c * 4);
  }
  float x80 = (qq == 0) ? lp[80] : -INFINITY;
  float m = x80;
  #pragma unroll
  for (int j = 0; j < 5; j++)
    m = fmaxf(m, fmaxf(fmaxf(x[j].x, x[j].y), fmaxf(x[j].z, x[j].w)));
  m = fmaxf(m, __shfl_xor(m, 1));
  m = fmaxf(m, __shfl_xor(m, 2));
  float e = (qq == 0) ? expf(x80 - m) : 0.0f;
  #pragma unroll
  for (int j = 0; j < 5; j++)
    e += expf(x[j].x - m) + expf(x[j].y - m) + expf(x[j].z - m) + expf(x[j].w - m);
  e += __shfl_xor(e, 1);
  e += __shfl_xor(e, 2);
  float bv = -INFINITY; int bi = 0x7fffffff;
  #pragma unroll
  for (int j = 0; j < 5; j++) {
    int base = (qq + 4 * j) * 4;
    if (x[j].x > bv) { bv = x[j].x; bi = base; }
    if (x[j].y > bv) { bv = x[j].y; bi = base + 1; }
    if (x[j].z > bv) { bv = x[j].z; bi = base + 2; }
    if (x[j].w > bv) { bv = x[j].w; bi = base + 3; }
  }
  #pragma unroll
  for (int s = 1; s <= 2; s <<= 1) {
    float ov = __shfl_xor(bv, s); int oi = __shfl_xor(bi, s);
    if (ov > bv || (ov == bv && oi < bi)) { bv = ov; bi = oi; }
  }
  if (qq == 0) {
    scores[row] = expf(bv - m) / e;
    labels[row] = bi;
  }
}

// ---------------- K2: per-(image,class) greedy NMS, LDS-pipelined ----------------
// One wave per (img,class). All cross-lane traffic via LDS broadcast reads
// (address independent of loop-carried state -> pipelines with unroll), no
// runtime-bound shfl chains. Wave-synchronous LDS: no barriers needed intra-wave.
__global__ __launch_bounds__(256) void k_cnms(const float* __restrict__ scores,
                                              const int* __restrict__ labels,
                                              const float* __restrict__ boxes,
                                              float* __restrict__ hsc,
                                              float* __restrict__ osc) {
#pragma clang fp contract(off)
  int img = blockIdx.x;
  int tid = threadIdx.x;
  int wid = tid >> 6, lane = tid & 63;
  int c = blockIdx.y * 4 + wid;
  size_t imgQ = (size_t)img * Q;
  __shared__ float  s_sc[4][64];     // compacted member scores (gather order)
  __shared__ int    s_idx[4][64];    // compacted member indices (gather order)
  __shared__ int    s_srt[4][64];    // sorted: original index
  __shared__ float  s_ssc[4][64];    // sorted: score
  __shared__ float4 s_sb[4][64];     // sorted: offset box
  __shared__ unsigned long long s_sup[4][64];  // suppression rows
  __shared__ float  s_wmax[4];

  // per-image box max (order-independent, bit-exact)
  const float4* bp4 = (const float4*)(boxes + imgQ * 4);
  float bm = -INFINITY;
  for (int i = tid; i < Q; i += 256) {
    float4 v = bp4[i];
    bm = fmaxf(bm, fmaxf(fmaxf(v.x, v.y), fmaxf(v.z, v.w)));
  }
  #pragma unroll
  for (int s = 32; s > 0; s >>= 1) bm = fmaxf(bm, __shfl_xor(bm, s));
  if (lane == 0) s_wmax[wid] = bm;
  __syncthreads();
  float bmax = fmaxf(fmaxf(s_wmax[0], s_wmax[1]), fmaxf(s_wmax[2], s_wmax[3]));

  // prefetch labels/scores (independent loads, pipelined), then ballot-compact
  int lb[15]; float sc[15];
  #pragma unroll
  for (int e = 0; e < 15; e++) {
    int i = e * 64 + lane;
    lb[e] = (i < Q) ? labels[imgQ + i] : -1;
    sc[e] = (i < Q) ? scores[imgQ + i] : 0.0f;
  }
  unsigned long long lmask = (1ull << lane) - 1ull;
  int n = 0;
  #pragma unroll
  for (int e = 0; e < 15; e++) {
    bool memb = (lb[e] == c);
    unsigned long long mm = __ballot(memb);
    if (memb) {
      int pos = n + __popcll(mm & lmask);
      if (pos < 64) { s_idx[wid][pos] = e * 64 + lane; s_sc[wid][pos] = sc[e]; }
    }
    n += __popcll(mm);
  }
  n = min(n, 64);

  int   myidx = (lane < n) ? s_idx[wid][lane] : 0;
  float mysc  = (lane < n) ? s_sc[wid][lane]  : -INFINITY;

  // stable rank via LDS broadcast reads (score desc, index asc; gather order is index-asc)
  int rank = 0;
  #pragma unroll 4
  for (int j = 0; j < n; j++) {
    float sj = s_sc[wid][j];
    rank += (sj > mysc) || (sj == mysc && j < lane);
  }

  // scatter sorted: index, score, offset box (per-element +off matches ref rounding)
  if (lane < n) {
    float off = (float)c * (bmax + 1.0f);
    const float* bp = boxes + (imgQ + myidx) * 4;
    float4 b;
    b.x = bp[0] + off; b.y = bp[1] + off;
    b.z = bp[2] + off; b.w = bp[3] + off;
    s_srt[wid][rank] = myidx;
    s_ssc[wid][rank] = mysc;
    s_sb[wid][rank]  = b;
  }

  // my sorted box
  float4 mb = (lane < n) ? s_sb[wid][lane] : float4{0.f, 0.f, 0.f, 0.f};
  float areaA = (mb.z - mb.x) * (mb.w - mb.y);

  // suppression row via LDS broadcast reads (pipelined)
  unsigned long long sup = 0;
  #pragma unroll 4
  for (int j = 0; j < n; j++) {
    float4 cb = s_sb[wid][j];
    if (j > lane && lane < n) {
      float ltx = fmaxf(mb.x, cb.x), lty = fmaxf(mb.y, cb.y);
      float rbx = fminf(mb.z, cb.z), rby = fminf(mb.w, cb.w);
      float ww = fmaxf(rbx - ltx, 0.0f), hh = fmaxf(rby - lty, 0.0f);
      float inter = ww * hh;
      float areaB = (cb.z - cb.x) * (cb.w - cb.y);
      float uni = areaA + areaB - inter;
      float denom = (uni == 0.0f) ? 1.0f : uni;
      if (inter / denom > 0.5f) sup |= (1ull << j);
    }
  }
  s_sup[wid][lane] = sup;

  // greedy sweep: every lane redundantly replays the chain from LDS broadcast rows
  // (row addresses independent of keepm -> reads pipeline; update is 2 VALU ops)
  unsigned long long keepm = (n >= 64) ? ~0ull : ((1ull << n) - 1ull);
  #pragma unroll 4
  for (int i = 0; i < n; i++) {
    unsigned long long row = s_sup[wid][i];
    if ((keepm >> i) & 1ull) keepm &= ~row;
  }

  if (lane < n) {
    int kept = (int)((keepm >> lane) & 1ull);
    int   oi = s_srt[wid][lane];
    float os = s_ssc[wid][lane];
    hsc[imgQ + oi] = (kept && c == 0) ? os : NEGV;
    osc[imgQ + oi] = (kept && c != 0) ? os : NEGV;
  }
}

// ---------------- K3: topk + GEMM slice + epilogue (1 block per img,slice) -------
// Packed output cols: [0,117) = Wv verb, [117,125) = Wb bbox. Slice s owns packed
// cols [s*32, s*32+32). Ch rows (h) use W rows 0..255, Co rows (o) 256..511.
__global__ __launch_bounds__(1024) void k_back(const float* __restrict__ hscg,
                                               const float* __restrict__ oscg,
                                               const float* __restrict__ boxes,
                                               const float* __restrict__ hs,
                                               const float* __restrict__ sizes,
                                               const float* __restrict__ Wv,
                                               const float* __restrict__ bverb,
                                               const float* __restrict__ Wb,
                                               const float* __restrict__ bbox,
                                               float* __restrict__ out) {
  int slice = blockIdx.x, img = blockIdx.y;
  int t = threadIdx.x, w = t >> 6, lane = t & 63;
  size_t imgQ = (size_t)img * Q;

  __shared__ __attribute__((aligned(16))) float s_A[30 * 256];
  __shared__ float s_B[2][64][32];           // B chunk: [h/o][k][c]
  __shared__ float s_Cg[30][32];
  __shared__ int   s_tki[30];
  __shared__ float s_tkv[30];
  __shared__ int   s_tkval[30];
  __shared__ float s_pr[225];
  __shared__ float s_box30[120];

  // ---- topk: wave0 = humans, wave1 = objects (other waves wait) ----
  if (w < 2) {
    const float* src = (w == 0) ? hscg : oscg;
    float v[15];
    int cnt = 0;
    #pragma unroll
    for (int e = 0; e < 15; e++) {
      int i = e * 64 + lane;
      float val = (i < Q) ? src[imgQ + i] : -INFINITY;
      cnt += (val >= 0.2f) ? 1 : 0;
      v[e] = val;
    }
    #pragma unroll
    for (int s = 32; s > 0; s >>= 1) cnt += __shfl_xor(cnt, s);

    float selv = 0.f; int seli = 0;
    for (int r = 0; r < 15; r++) {
      float bv_ = -INFINITY; int bi_ = 0x7fffffff;
      #pragma unroll
      for (int e = 0; e < 15; e++) { if (v[e] > bv_) { bv_ = v[e]; bi_ = e * 64 + lane; } }
      #pragma unroll
      for (int s = 32; s > 0; s >>= 1) {
        float ov = __shfl_xor(bv_, s); int oi2 = __shfl_xor(bi_, s);
        if (ov > bv_ || (ov == bv_ && oi2 < bi_)) { bv_ = ov; bi_ = oi2; }
      }
      if (lane == r) { selv = bv_; seli = bi_; }
      if ((bi_ & 63) == lane) {
        int ee = bi_ >> 6;
        #pragma unroll
        for (int e = 0; e < 15; e++) if (e == ee) v[e] = -2.0e9f;
      }
    }
    int kk = min(max(cnt, 3), 15);
    if (lane < 15) {
      s_tki[w * 15 + lane]   = seli;
      s_tkv[w * 15 + lane]   = selv;
      s_tkval[w * 15 + lane] = (lane < kk && selv > -5.0e8f) ? 1 : 0;
    }
  }
  __syncthreads();

  // ---- pair products + snapshot selected boxes ----
  if (t < 225) {
    int h_ = t / 15, o_ = t - h_ * 15;
    float th = s_tkv[h_], to_ = s_tkv[15 + o_];
    s_pr[t] = (s_tkval[h_] && s_tkval[15 + o_]) ? th * to_ : 0.0f;
  }
  if (t < 120) {
    int r = t >> 2, j = t & 3;
    s_box30[t] = boxes[(imgQ + s_tki[r]) * 4 + j];
  }

  // ---- stage A (30 gathered hs rows) ----
  for (int f = t; f < 1920; f += 1024) {
    int r = f >> 6, q = f & 63;
    float4 a = *(const float4*)(hs + (imgQ + s_tki[r]) * HD + q * 4);
    ((float4*)s_A)[r * 64 + q] = a;
  }

  // ---- GEMM: 30 rows x 32 packed cols, K chunked by 64 ----
  int r = t >> 5, c = t & 31;                // GEMM output coords (r<30)
  float acc = 0.0f;
  for (int kc = 0; kc < 256; kc += 64) {
    __syncthreads();                          // A/s_box30 ready; prev B consumed
    for (int idx = t; idx < 4096; idx += 1024) {
      int half = idx >> 11, rem = idx & 2047;
      int k_l = rem >> 5, c_l = rem & 31;
      int pcol = slice * 32 + c_l;
      int kg = kc + k_l + (half ? 256 : 0);
      float val = 0.0f;
      if (pcol < 117)      val = Wv[(size_t)kg * 117 + pcol];
      else if (pcol < 125) val = Wb[(size_t)kg * 8 + (pcol - 117)];
      s_B[half][k_l][c_l] = val;
    }
    __syncthreads();
    if (r < 30) {
      const float* Bp = &s_B[r < 15 ? 0 : 1][0][0];
      #pragma unroll
      for (int kk = 0; kk < 64; kk += 4) {
        float4 a4 = *(const float4*)(s_A + r * 256 + kc + kk);
        acc += a4.x * Bp[(kk + 0) * 32 + c];
        acc += a4.y * Bp[(kk + 1) * 32 + c];
        acc += a4.z * Bp[(kk + 2) * 32 + c];
        acc += a4.w * Bp[(kk + 3) * 32 + c];
      }
    }
  }
  if (r < 30) s_Cg[r][c] = acc;
  __syncthreads();

  // ---- epilogue ----
  float hgt = sizes[img * 2 + 0], wid = sizes[img * 2 + 1];
  float* out0 = out;
  float* out1 = out + 7680;
  float* out2 = out + 65280;
  float* out3 = out + 122880;

  int veff = (slice < 3) ? 32 : 21;          // slice 3: packed cols 96..116 are verb
  for (int e = t; e < 225 * veff; e += 1024) {
    int p = e / veff, cl = e - p * veff;
    int ph = p / 15, po = p - ph * 15;
    int v = slice * 32 + cl;
    float x = s_Cg[ph][cl] + s_Cg[15 + po][cl] + bverb[v];
    out3[(size_t)img * 26325 + p * NV + v] = (1.0f / (1.0f + expf(-x))) * s_pr[p];
  }

  if (slice == 3) {
    if (t < 30) {
      const float* bp = s_box30 + t * 4;
      float cx = bp[0], cy = bp[1], ww = bp[2], hh = bp[3];
      float* o = out0 + ((size_t)img * 30 + t) * 4;
      o[0] = (cx - 0.5f * ww) * wid;
      o[1] = (cy - 0.5f * hh) * hgt;
      o[2] = (cx + 0.5f * ww) * wid;
      o[3] = (cy + 0.5f * hh) * hgt;
    }
    if (t < 225) {
      int h_ = t / 15, o_ = t - h_ * 15;
      // bbox cols are packed 117..124 -> local 21..28 on slice 3
      {
        float d0 = s_Cg[h_][21] + s_Cg[15 + o_][21] + bbox[0];
        float d1 = s_Cg[h_][22] + s_Cg[15 + o_][22] + bbox[1];
        float d2 = s_Cg[h_][23] + s_Cg[15 + o_][23] + bbox[2];
        float d3 = s_Cg[h_][24] + s_Cg[15 + o_][24] + bbox[3];
        const float* bp = s_box30 + h_ * 4;
        float cx = bp[0], cy = bp[1], ww = bp[2], hh = bp[3];
        float cx2 = cx + d0 * ww, cy2 = cy + d1 * hh;
        float w2 = ww * expf(d2), h2 = hh * expf(d3);
        float* o = out1 + ((size_t)img * 225 + t) * 4;
        o[0] = (cx2 - 0.5f * w2) * wid;
        o[1] = (cy2 - 0.5f * h2) * hgt;
        o[2] = (cx2 + 0.5f * w2) * wid;
        o[3] = (cy2 + 0.5f * h2) * hgt;
      }
      {
        float d4 = s_Cg[h_][25] + s_Cg[15 + o_][25] + bbox[4];
        float d5 = s_Cg[h_][26] + s_Cg[15 + o_][26] + bbox[5];
        float d6 = s_Cg[h_][27] + s_Cg[15 + o_][27] + bbox[6];
        float d7 = s_Cg[h_][28] + s_Cg[15 + o_][28] + bbox[7];
        const float* bp = s_box30 + (15 + o_) * 4;
        float cx = bp[0], cy = bp[1], ww = bp[2], hh = bp[3];
        float cx2 = cx + d4 * ww, cy2 = cy + d5 * hh;
        float w2 = ww * expf(d6), h2 = hh * expf(d7);
        float* o = out2 + ((size_t)img * 225 + t) * 4;
        o[0] = (cx2 - 0.5f * w2) * wid;
        o[1] = (cy2 - 0.5f * h2) * hgt;
        o[2] = (cx2 + 0.5f * w2) * wid;
        o[3] = (cy2 + 0.5f * h2) * hgt;
      }
    }
  }
}

extern "C" void kernel_launch(void* const* d_in, const int* in_sizes, int n_in,
                              void* d_out, int out_size, void* d_ws, size_t ws_size,
                              hipStream_t stream) {
  const float* logits = (const float*)d_in[0];
  const float* boxes  = (const float*)d_in[1];
  const float* hs     = (const float*)d_in[2];
  const float* sizes  = (const float*)d_in[3];
  const float* Wv     = (const float*)d_in[4];
  const float* bv     = (const float*)d_in[5];
  const float* Wb     = (const float*)d_in[6];
  const float* bb     = (const float*)d_in[7];
  float* out = (float*)d_out;
  char* ws = (char*)d_ws;

  float* scores = (float*)(ws + OFF_SCORES);
  int*   labels = (int*)(ws + OFF_LABELS);
  float* hsc    = (float*)(ws + OFF_HSC);
  float* osc    = (float*)(ws + OFF_OSC);

  k_score<<<900, 256, 0, stream>>>(logits, scores, labels);
  k_cnms<<<dim3(NB, 20), 256, 0, stream>>>(scores, labels, boxes, hsc, osc);
  k_back<<<dim3(4, NB), 1024, 0, stream>>>(hsc, osc, boxes, hs, sizes,
                                           Wv, bv, Wb, bb, out);
}